// Round 1
// baseline (1882.046 us; speedup 1.0000x reference)
//
#include <hip/hip_runtime.h>

#define NSEQ  1024
#define NHEAD 12
#define HDIM  64
#define CDIM  768
#define BATCH 8

// ---------------- GEMM: C[M,N] = A[M,K] @ W[N,K]^T, K=768 ----------------
// 128x128 tile, BK=16, 256 threads, 8x8 micro-tile.
// MODE 0: qkv epilogue -> q (scaled 1/8, [b,h,q,d]), k (transposed [b,h,d,q]), v ([b,h,k,d])
// MODE 1: plain C write (out-projection)
template<int MODE>
__global__ __launch_bounds__(256)
void gemm_xwt(const float* __restrict__ A, const float* __restrict__ W,
              float* __restrict__ O0, float* __restrict__ O1,
              float* __restrict__ O2)
{
  constexpr int K = 768;
  __shared__ float As[16][132];
  __shared__ float Bs[16][132];
  const int t  = threadIdx.x;
  const int tx = t & 15;
  const int ty = t >> 4;
  const int bn = blockIdx.x;
  const int bm = blockIdx.y;
  const float* Ab = A + (size_t)bm * 128 * K;
  const float* Wb = W + (size_t)bn * 128 * K;

  float acc[8][8];
#pragma unroll
  for (int i = 0; i < 8; ++i)
#pragma unroll
    for (int j = 0; j < 8; ++j) acc[i][j] = 0.f;

  for (int k0 = 0; k0 < K; k0 += 16) {
#pragma unroll
    for (int r = 0; r < 2; ++r) {
      int idx = r * 256 + t;
      int row = idx >> 2;
      int kq  = (idx & 3) << 2;
      float4 av = *(const float4*)(Ab + (size_t)row * K + (k0 + kq));
      As[kq + 0][row] = av.x;
      As[kq + 1][row] = av.y;
      As[kq + 2][row] = av.z;
      As[kq + 3][row] = av.w;
      float4 bv = *(const float4*)(Wb + (size_t)row * K + (k0 + kq));
      Bs[kq + 0][row] = bv.x;
      Bs[kq + 1][row] = bv.y;
      Bs[kq + 2][row] = bv.z;
      Bs[kq + 3][row] = bv.w;
    }
    __syncthreads();
#pragma unroll
    for (int kk = 0; kk < 16; ++kk) {
      float a[8], bb[8];
      *(float4*)(a)      = *(const float4*)&As[kk][ty * 8];
      *(float4*)(a + 4)  = *(const float4*)&As[kk][ty * 8 + 4];
      *(float4*)(bb)     = *(const float4*)&Bs[kk][tx * 8];
      *(float4*)(bb + 4) = *(const float4*)&Bs[kk][tx * 8 + 4];
#pragma unroll
      for (int i = 0; i < 8; ++i)
#pragma unroll
        for (int j = 0; j < 8; ++j) acc[i][j] += a[i] * bb[j];
    }
    __syncthreads();
  }

  if (MODE == 1) {
#pragma unroll
    for (int i = 0; i < 8; ++i) {
      size_t off = (size_t)(bm * 128 + ty * 8 + i) * 768 + bn * 128 + tx * 8;
      float4 w0 = {acc[i][0], acc[i][1], acc[i][2], acc[i][3]};
      float4 w1 = {acc[i][4], acc[i][5], acc[i][6], acc[i][7]};
      *(float4*)(O0 + off)     = w0;
      *(float4*)(O0 + off + 4) = w1;
    }
  } else {
    const int nbase = bn * 128 + tx * 8;
    const int sec   = nbase / 768;   // 2304 = 18*128, 768 = 6*128 -> uniform per block
#pragma unroll
    for (int i = 0; i < 8; ++i) {
      int m  = bm * 128 + ty * 8 + i;
      int bb = m >> 10;
      int qi = m & 1023;
#pragma unroll
      for (int j = 0; j < 8; ++j) {
        int r = nbase + j - sec * 768;
        int h = r >> 6;
        int d = r & 63;
        float v = acc[i][j];
        if (sec == 0) {
          O0[(((size_t)(bb * 12 + h)) * 1024 + qi) * 64 + d] = v * 0.125f; // q, pre-scaled
        } else if (sec == 1) {
          O1[(((size_t)(bb * 12 + h)) * 64 + d) * 1024 + qi] = v;          // k, d-major
        } else {
          O2[(((size_t)(bb * 12 + h)) * 1024 + qi) * 64 + d] = v;          // v
        }
      }
    }
  }
}

// ---------------- fused attention + importance ----------------
// block = (b, 8-query tile), 256 threads, loops over 12 heads.
// thread owns k-quad kq = ko*256 + lane*4 for S rows and AW accumulation.
struct SmemA {
  float S[8][1024];    // softmaxed probabilities of current head
  float Qs[8][64];
  float Ctx[8][64];
  float wred[64];      // [0..31] max-reduce, [32..63] sum-reduce
};
union SmemU {
  SmemA a;
  float AWf[8][1024];  // aliased over S: only used after the head loop
};

__global__ __launch_bounds__(256)
void attn_kernel(const float* __restrict__ Qw, const float* __restrict__ Kt,
                 const float* __restrict__ Vw, float* __restrict__ CtxG,
                 float* __restrict__ Imp)
{
  __shared__ SmemU sm;
  const int t    = threadIdx.x;
  const int qt   = blockIdx.x;   // 0..127
  const int b    = blockIdx.y;   // 0..7
  const int q0   = qt * 8;
  const int lane = t & 63;
  const int ko   = t >> 6;       // wave id 0..3
  const int kq   = ko * 256 + lane * 4;

  float aw[8][4];
#pragma unroll
  for (int qi = 0; qi < 8; ++qi)
#pragma unroll
    for (int c = 0; c < 4; ++c) aw[qi][c] = 0.f;

  for (int h = 0; h < 12; ++h) {
    const float* Qh = Qw + (((size_t)b * 12 + h) * 1024 + q0) * 64;
    const float* Kh = Kt + ((size_t)b * 12 + h) * 64 * 1024;
    const float* Vh = Vw + ((size_t)b * 12 + h) * 1024 * 64;

    __syncthreads();                       // prev iter done with Qs/Ctx
    for (int i = t; i < 512; i += 256) {
      (&sm.a.Qs[0][0])[i]  = Qh[i];
      (&sm.a.Ctx[0][0])[i] = 0.f;
    }
    __syncthreads();

    // ---- S = q k^T (q pre-scaled by 1/8) ----
    float s[8][4];
#pragma unroll
    for (int qi = 0; qi < 8; ++qi) {
      s[qi][0] = 0.f; s[qi][1] = 0.f; s[qi][2] = 0.f; s[qi][3] = 0.f;
    }
    for (int d4 = 0; d4 < 64; d4 += 4) {
      float4 k0v = *(const float4*)(Kh + (size_t)(d4 + 0) * 1024 + kq);
      float4 k1v = *(const float4*)(Kh + (size_t)(d4 + 1) * 1024 + kq);
      float4 k2v = *(const float4*)(Kh + (size_t)(d4 + 2) * 1024 + kq);
      float4 k3v = *(const float4*)(Kh + (size_t)(d4 + 3) * 1024 + kq);
#pragma unroll
      for (int qi = 0; qi < 8; ++qi) {
        float4 qv = *(const float4*)&sm.a.Qs[qi][d4];
        s[qi][0] += qv.x * k0v.x + qv.y * k1v.x + qv.z * k2v.x + qv.w * k3v.x;
        s[qi][1] += qv.x * k0v.y + qv.y * k1v.y + qv.z * k2v.y + qv.w * k3v.y;
        s[qi][2] += qv.x * k0v.z + qv.y * k1v.z + qv.z * k2v.z + qv.w * k3v.z;
        s[qi][3] += qv.x * k0v.w + qv.y * k1v.w + qv.z * k2v.w + qv.w * k3v.w;
      }
    }

    // ---- softmax over k ----
#pragma unroll
    for (int qi = 0; qi < 8; ++qi) {
      float m = fmaxf(fmaxf(s[qi][0], s[qi][1]), fmaxf(s[qi][2], s[qi][3]));
#pragma unroll
      for (int off = 32; off > 0; off >>= 1)
        m = fmaxf(m, __shfl_xor(m, off));
      if (lane == 0) sm.a.wred[qi * 4 + ko] = m;
    }
    __syncthreads();
#pragma unroll
    for (int qi = 0; qi < 8; ++qi) {
      float m = fmaxf(fmaxf(sm.a.wred[qi * 4 + 0], sm.a.wred[qi * 4 + 1]),
                      fmaxf(sm.a.wred[qi * 4 + 2], sm.a.wred[qi * 4 + 3]));
      float e0 = __expf(s[qi][0] - m);
      float e1 = __expf(s[qi][1] - m);
      float e2 = __expf(s[qi][2] - m);
      float e3 = __expf(s[qi][3] - m);
      s[qi][0] = e0; s[qi][1] = e1; s[qi][2] = e2; s[qi][3] = e3;
      float ls = (e0 + e1) + (e2 + e3);
#pragma unroll
      for (int off = 32; off > 0; off >>= 1)
        ls += __shfl_xor(ls, off);
      if (lane == 0) sm.a.wred[32 + qi * 4 + ko] = ls;
    }
    __syncthreads();
#pragma unroll
    for (int qi = 0; qi < 8; ++qi) {
      float tot = (sm.a.wred[32 + qi * 4 + 0] + sm.a.wred[32 + qi * 4 + 1]) +
                  (sm.a.wred[32 + qi * 4 + 2] + sm.a.wred[32 + qi * 4 + 3]);
      float inv = 1.f / tot;
      float4 p;
      p.x = s[qi][0] * inv;
      p.y = s[qi][1] * inv;
      p.z = s[qi][2] * inv;
      p.w = s[qi][3] * inv;
      *(float4*)&sm.a.S[qi][kq] = p;
      aw[qi][0] += p.x * (1.f / 12.f);
      aw[qi][1] += p.y * (1.f / 12.f);
      aw[qi][2] += p.z * (1.f / 12.f);
      aw[qi][3] += p.w * (1.f / 12.f);
    }
    __syncthreads();                       // S visible

    // ---- ctx = P V ----  (lane = d, ko = k-slice of 256)
    float cacc[8];
#pragma unroll
    for (int qi = 0; qi < 8; ++qi) cacc[qi] = 0.f;
    const float* Vb = Vh + (size_t)ko * 256 * 64 + lane;
    for (int k4 = 0; k4 < 256; k4 += 4) {
      float v0 = Vb[(size_t)(k4 + 0) * 64];
      float v1 = Vb[(size_t)(k4 + 1) * 64];
      float v2 = Vb[(size_t)(k4 + 2) * 64];
      float v3 = Vb[(size_t)(k4 + 3) * 64];
      const int kk = ko * 256 + k4;
#pragma unroll
      for (int qi = 0; qi < 8; ++qi) {
        float4 p = *(const float4*)&sm.a.S[qi][kk];  // broadcast read
        cacc[qi] += p.x * v0 + p.y * v1 + p.z * v2 + p.w * v3;
      }
    }
#pragma unroll
    for (int qi = 0; qi < 8; ++qi) atomicAdd(&sm.a.Ctx[qi][lane], cacc[qi]);
    __syncthreads();
    for (int i = t; i < 512; i += 256) {
      int qi = i >> 6, d = i & 63;
      CtxG[((size_t)b * 1024 + q0 + qi) * 768 + h * 64 + d] = sm.a.Ctx[qi][d];
    }
  }

  __syncthreads();
  // ---- importance from head-mean attention (AW aliased over S) ----
#pragma unroll
  for (int qi = 0; qi < 8; ++qi) {
    float4 w = {aw[qi][0], aw[qi][1], aw[qi][2], aw[qi][3]};
    *(float4*)&sm.AWf[qi][kq] = w;
  }
  __syncthreads();

  float ia[4] = {0.f, 0.f, 0.f, 0.f};
#pragma unroll
  for (int qi = 0; qi < 8; ++qi) {
#pragma unroll
    for (int c = 0; c < 4; ++c) {
      int k = kq + c;
      float am = sm.AWf[qi][k == 0 ? 0 : k - 1];
      float ap = sm.AWf[qi][k == 1023 ? 1023 : k + 1];
      ia[c] += fabsf((ap - am) * 0.5f);
    }
  }
#pragma unroll
  for (int c = 0; c < 4; ++c) atomicAdd(&Imp[b * 1024 + kq + c], ia[c]);
}

// ---------------- conv3 + standardize + softmax(fs/0.1) ----------------
__device__ inline float blk_sum(float v, volatile float* wbuf, int t) {
#pragma unroll
  for (int off = 32; off > 0; off >>= 1) v += __shfl_xor(v, off);
  __syncthreads();
  if ((t & 63) == 0) wbuf[t >> 6] = v;
  __syncthreads();
  return (wbuf[0] + wbuf[1]) + (wbuf[2] + wbuf[3]);
}
__device__ inline float blk_max(float v, volatile float* wbuf, int t) {
#pragma unroll
  for (int off = 32; off > 0; off >>= 1) v = fmaxf(v, __shfl_xor(v, off));
  __syncthreads();
  if ((t & 63) == 0) wbuf[t >> 6] = v;
  __syncthreads();
  return fmaxf(fmaxf(wbuf[0], wbuf[1]), fmaxf(wbuf[2], wbuf[3]));
}

__global__ __launch_bounds__(256)
void scores_kernel(const float* __restrict__ Imp, const float* __restrict__ smw,
                   float* __restrict__ Out)
{
  __shared__ float ip[1026];
  __shared__ float wbuf[4];
  const int b = blockIdx.x;
  const int t = threadIdx.x;

  if (t == 0) { ip[0] = 0.f; ip[1025] = 0.f; }
  float4 iv = *(const float4*)(Imp + (size_t)b * 1024 + t * 4);
  ip[1 + t * 4 + 0] = iv.x;
  ip[1 + t * 4 + 1] = iv.y;
  ip[1 + t * 4 + 2] = iv.z;
  ip[1 + t * 4 + 3] = iv.w;
  __syncthreads();

  const float w0 = smw[0], w1 = smw[1], w2 = smw[2];
  float smv[4];
#pragma unroll
  for (int j = 0; j < 4; ++j) {
    int k = t * 4 + j;
    smv[j] = w0 * ip[k] + w1 * ip[k + 1] + w2 * ip[k + 2];  // zero-padded conv
  }
  float tot = blk_sum((smv[0] + smv[1]) + (smv[2] + smv[3]), wbuf, t);
  float mu  = tot * (1.f / 1024.f);
  float lv = 0.f;
#pragma unroll
  for (int j = 0; j < 4; ++j) { float d = smv[j] - mu; lv += d * d; }
  float var = blk_sum(lv, wbuf, t) * (1.f / 1023.f);       // ddof=1
  float inv = 1.f / (sqrtf(var) + 1e-6f);
  float fs[4];
#pragma unroll
  for (int j = 0; j < 4; ++j) fs[j] = (smv[j] - mu) * inv * 10.f;  // /TEMP
  float M = blk_max(fmaxf(fmaxf(fs[0], fs[1]), fmaxf(fs[2], fs[3])), wbuf, t);
  float e[4]; float ls = 0.f;
#pragma unroll
  for (int j = 0; j < 4; ++j) { e[j] = __expf(fs[j] - M); ls += e[j]; }
  float S = blk_sum(ls, wbuf, t);
  float r = 1.f / S;
  float4 o = {e[0] * r, e[1] * r, e[2] * r, e[3] * r};
  *(float4*)(Out + (size_t)b * 1024 + t * 4) = o;
}

extern "C" void kernel_launch(void* const* d_in, const int* in_sizes, int n_in,
                              void* d_out, int out_size, void* d_ws, size_t ws_size,
                              hipStream_t stream)
{
  const float* x     = (const float*)d_in[0];
  const float* w_in  = (const float*)d_in[1];
  const float* w_out = (const float*)d_in[2];
  const float* smw   = (const float*)d_in[3];
  float* out = (float*)d_out;

  const size_t SZ = (size_t)BATCH * NSEQ * CDIM;   // 6291456
  float* q_ws   = (float*)d_ws;
  float* k_ws   = q_ws + SZ;
  float* v_ws   = k_ws + SZ;
  float* ctx_ws = v_ws + SZ;
  float* imp    = ctx_ws + SZ;                     // 8192 floats

  hipMemsetAsync(imp, 0, BATCH * NSEQ * sizeof(float), stream);

  gemm_xwt<0><<<dim3(18, 64), 256, 0, stream>>>(x, w_in, q_ws, k_ws, v_ws);
  attn_kernel<<<dim3(128, 8), 256, 0, stream>>>(q_ws, k_ws, v_ws, ctx_ws, imp);
  gemm_xwt<1><<<dim3(6, 64), 256, 0, stream>>>(ctx_ws, w_out, out, nullptr, nullptr);
  scores_kernel<<<8, 256, 0, stream>>>(imp, smw, out + SZ);
}

// Round 2
// 865.534 us; speedup vs baseline: 2.1744x; 2.1744x over previous
//
#include <hip/hip_runtime.h>

#define NSEQ  1024
#define NHEAD 12
#define HDIM  64
#define CDIM  768
#define BATCH 8

typedef short bf16x8 __attribute__((ext_vector_type(8)));
typedef float f32x4  __attribute__((ext_vector_type(4)));

__device__ __forceinline__ float bf2f(unsigned short h) {
  unsigned u = ((unsigned)h) << 16;
  float f;
  __builtin_memcpy(&f, &u, 4);
  return f;
}
__device__ __forceinline__ unsigned short f2bf(float f) {
  unsigned u;
  __builtin_memcpy(&u, &f, 4);
  u = (u + 0x7fffu + ((u >> 16) & 1u)) >> 16;
  return (unsigned short)u;
}

// ---------------- GEMM: C[M,N] = A[M,K] @ W[N,K]^T, K=768 ----------------
// MODE 0: qkv epilogue -> qhi/qlo bf16 [b,h,q,d] (pre-scaled 1/8),
//         khi/klo bf16 [b,h,k,d], vt bf16 [b,h,d,k]
// MODE 1: plain fp32 C write (out-projection)
template<int MODE>
__global__ __launch_bounds__(256)
void gemm_xwt(const float* __restrict__ A, const float* __restrict__ W,
              float* __restrict__ C,
              unsigned short* __restrict__ Qhi, unsigned short* __restrict__ Qlo,
              unsigned short* __restrict__ Khi, unsigned short* __restrict__ Klo,
              unsigned short* __restrict__ Vt)
{
  constexpr int K = 768;
  __shared__ float As[16][132];
  __shared__ float Bs[16][132];
  const int t  = threadIdx.x;
  const int tx = t & 15;
  const int ty = t >> 4;
  const int bn = blockIdx.x;
  const int bm = blockIdx.y;
  const float* Ab = A + (size_t)bm * 128 * K;
  const float* Wb = W + (size_t)bn * 128 * K;

  float acc[8][8];
#pragma unroll
  for (int i = 0; i < 8; ++i)
#pragma unroll
    for (int j = 0; j < 8; ++j) acc[i][j] = 0.f;

  for (int k0 = 0; k0 < K; k0 += 16) {
#pragma unroll
    for (int r = 0; r < 2; ++r) {
      int idx = r * 256 + t;
      int row = idx >> 2;
      int kq  = (idx & 3) << 2;
      float4 av = *(const float4*)(Ab + (size_t)row * K + (k0 + kq));
      As[kq + 0][row] = av.x;
      As[kq + 1][row] = av.y;
      As[kq + 2][row] = av.z;
      As[kq + 3][row] = av.w;
      float4 bv = *(const float4*)(Wb + (size_t)row * K + (k0 + kq));
      Bs[kq + 0][row] = bv.x;
      Bs[kq + 1][row] = bv.y;
      Bs[kq + 2][row] = bv.z;
      Bs[kq + 3][row] = bv.w;
    }
    __syncthreads();
#pragma unroll
    for (int kk = 0; kk < 16; ++kk) {
      float a[8], bb[8];
      *(float4*)(a)      = *(const float4*)&As[kk][ty * 8];
      *(float4*)(a + 4)  = *(const float4*)&As[kk][ty * 8 + 4];
      *(float4*)(bb)     = *(const float4*)&Bs[kk][tx * 8];
      *(float4*)(bb + 4) = *(const float4*)&Bs[kk][tx * 8 + 4];
#pragma unroll
      for (int i = 0; i < 8; ++i)
#pragma unroll
        for (int j = 0; j < 8; ++j) acc[i][j] += a[i] * bb[j];
    }
    __syncthreads();
  }

  if (MODE == 1) {
#pragma unroll
    for (int i = 0; i < 8; ++i) {
      size_t off = (size_t)(bm * 128 + ty * 8 + i) * 768 + bn * 128 + tx * 8;
      float4 w0 = {acc[i][0], acc[i][1], acc[i][2], acc[i][3]};
      float4 w1 = {acc[i][4], acc[i][5], acc[i][6], acc[i][7]};
      *(float4*)(C + off)     = w0;
      *(float4*)(C + off + 4) = w1;
    }
  } else {
    const int nbase = bn * 128 + tx * 8;
    const int sec   = nbase / 768;   // uniform per block (768 = 6*128)
#pragma unroll
    for (int i = 0; i < 8; ++i) {
      int m  = bm * 128 + ty * 8 + i;
      int bb = m >> 10;
      int qi = m & 1023;
#pragma unroll
      for (int j = 0; j < 8; ++j) {
        int r = nbase + j - sec * 768;
        int h = r >> 6;
        int d = r & 63;
        float v = acc[i][j];
        size_t bh = (size_t)(bb * 12 + h);
        if (sec == 0) {
          float f = v * 0.125f;                    // pre-scale q by 1/sqrt(64)
          unsigned short hi = f2bf(f);
          Qhi[(bh * 1024 + qi) * 64 + d] = hi;
          Qlo[(bh * 1024 + qi) * 64 + d] = f2bf(f - bf2f(hi));
        } else if (sec == 1) {
          unsigned short hi = f2bf(v);
          Khi[(bh * 1024 + qi) * 64 + d] = hi;
          Klo[(bh * 1024 + qi) * 64 + d] = f2bf(v - bf2f(hi));
        } else {
          Vt[(bh * 64 + d) * 1024 + qi] = f2bf(v); // transposed for PV B-operand
        }
      }
    }
  }
}

// ---------------- fused MFMA attention + importance ----------------
// block = (b, 16-query tile), 4 waves; wave w owns keys [w*256, w*256+256).
// QK^T: 3-pass bf16 hi/lo split (fp32-grade logits for the importance path).
// PV: single-bf16 P (LDS round trip, wave-local) x bf16 V^T.
struct AttnSmem {
  union {
    unsigned short P[16][1040];  // bf16 probs of current head (row-padded, 16B-aligned rows)
    float AW[8][1040];           // head-mean attention, one 8-row half at a time
  } u;
  float Cpart[4][16][64];        // per-wave PV partials
  float red[2][16][4];           // [0]=max, [1]=sum cross-wave softmax reduction
};

__global__ __launch_bounds__(256, 2)
void attn_mfma(const unsigned short* __restrict__ Qhi, const unsigned short* __restrict__ Qlo,
               const unsigned short* __restrict__ Khi, const unsigned short* __restrict__ Klo,
               const unsigned short* __restrict__ Vt,
               float* __restrict__ CtxG, float* __restrict__ Imp)
{
  __shared__ AttnSmem sm;
  const int t    = threadIdx.x;
  const int lane = t & 63;
  const int wid  = t >> 6;       // wave id: key slice
  const int g    = lane >> 4;    // quad within wave
  const int c    = lane & 15;
  const int qt   = blockIdx.x;   // 0..63
  const int b    = blockIdx.y;   // 0..7
  const int q0   = qt * 16;

  float aw[16][4];               // head-mean attn: key tile kt (col c), row g*4+r
#pragma unroll
  for (int kt = 0; kt < 16; ++kt)
#pragma unroll
    for (int r = 0; r < 4; ++r) aw[kt][r] = 0.f;

  for (int h = 0; h < 12; ++h) {
    const size_t bh = (size_t)b * 12 + h;

    // ---- Q fragments (A-operand: m=c, k=g*8+j) ----
    const unsigned short* qp_h = Qhi + (bh * 1024 + q0 + c) * 64 + g * 8;
    const unsigned short* qp_l = Qlo + (bh * 1024 + q0 + c) * 64 + g * 8;
    bf16x8 qh0 = *(const bf16x8*)qp_h;
    bf16x8 qh1 = *(const bf16x8*)(qp_h + 32);
    bf16x8 ql0 = *(const bf16x8*)qp_l;
    bf16x8 ql1 = *(const bf16x8*)(qp_l + 32);

    // ---- S = Q K^T over this wave's 256 keys: 16 tiles x 2 ksteps x 3 passes ----
    f32x4 acc[16];
#pragma unroll
    for (int kt = 0; kt < 16; ++kt) acc[kt] = (f32x4){0.f, 0.f, 0.f, 0.f};
    const unsigned short* kp_h = Khi + (bh * 1024 + wid * 256 + c) * 64 + g * 8;
    const unsigned short* kp_l = Klo + (bh * 1024 + wid * 256 + c) * 64 + g * 8;
#pragma unroll
    for (int kt = 0; kt < 16; ++kt) {
      const unsigned short* ph = kp_h + kt * 16 * 64;
      const unsigned short* pl = kp_l + kt * 16 * 64;
      bf16x8 kh0 = *(const bf16x8*)ph;
      bf16x8 kh1 = *(const bf16x8*)(ph + 32);
      bf16x8 kl0 = *(const bf16x8*)pl;
      bf16x8 kl1 = *(const bf16x8*)(pl + 32);
      f32x4 a = acc[kt];
      a = __builtin_amdgcn_mfma_f32_16x16x32_bf16(qh0, kh0, a, 0, 0, 0);
      a = __builtin_amdgcn_mfma_f32_16x16x32_bf16(qh1, kh1, a, 0, 0, 0);
      a = __builtin_amdgcn_mfma_f32_16x16x32_bf16(qh0, kl0, a, 0, 0, 0);
      a = __builtin_amdgcn_mfma_f32_16x16x32_bf16(qh1, kl1, a, 0, 0, 0);
      a = __builtin_amdgcn_mfma_f32_16x16x32_bf16(ql0, kh0, a, 0, 0, 0);
      a = __builtin_amdgcn_mfma_f32_16x16x32_bf16(ql1, kh1, a, 0, 0, 0);
      acc[kt] = a;
    }

    // ---- softmax over keys (C-layout: row q = g*4+r, col key = kt*16+c) ----
    float red4[4];
#pragma unroll
    for (int r = 0; r < 4; ++r) {
      float m = acc[0][r];
#pragma unroll
      for (int kt = 1; kt < 16; ++kt) m = fmaxf(m, acc[kt][r]);
      m = fmaxf(m, __shfl_xor(m, 1));
      m = fmaxf(m, __shfl_xor(m, 2));
      m = fmaxf(m, __shfl_xor(m, 4));
      m = fmaxf(m, __shfl_xor(m, 8));
      red4[r] = m;
    }
    if (c == 0) {
#pragma unroll
      for (int r = 0; r < 4; ++r) sm.red[0][g * 4 + r][wid] = red4[r];
    }
    __syncthreads();
    float M[4];
#pragma unroll
    for (int r = 0; r < 4; ++r) {
      const float* rp = sm.red[0][g * 4 + r];
      M[r] = fmaxf(fmaxf(rp[0], rp[1]), fmaxf(rp[2], rp[3]));
    }
    float sume[4];
#pragma unroll
    for (int r = 0; r < 4; ++r) {
      float s = 0.f;
#pragma unroll
      for (int kt = 0; kt < 16; ++kt) {
        float e = __expf(acc[kt][r] - M[r]);
        acc[kt][r] = e;
        s += e;
      }
      s += __shfl_xor(s, 1);
      s += __shfl_xor(s, 2);
      s += __shfl_xor(s, 4);
      s += __shfl_xor(s, 8);
      sume[r] = s;
    }
    if (c == 0) {
#pragma unroll
      for (int r = 0; r < 4; ++r) sm.red[1][g * 4 + r][wid] = sume[r];
    }
    __syncthreads();
#pragma unroll
    for (int r = 0; r < 4; ++r) {
      const float* rp = sm.red[1][g * 4 + r];
      float inv = 1.f / ((rp[0] + rp[1]) + (rp[2] + rp[3]));
#pragma unroll
      for (int kt = 0; kt < 16; ++kt) {
        float p = acc[kt][r] * inv;
        aw[kt][r] += p * (1.f / 12.f);
        sm.u.P[g * 4 + r][wid * 256 + kt * 16 + c] = f2bf(p);
      }
    }
    // no barrier: wave reads back only its own P columns below

    // ---- ctx partial: P[16 x 256] @ V^T -> C[16 q x 64 d] ----
    f32x4 cacc[4];
#pragma unroll
    for (int dt = 0; dt < 4; ++dt) cacc[dt] = (f32x4){0.f, 0.f, 0.f, 0.f};
    const unsigned short* vb = Vt + (bh * 64 + c) * 1024 + wid * 256 + g * 8;
#pragma unroll
    for (int ks = 0; ks < 8; ++ks) {
      bf16x8 pf = *(const bf16x8*)&sm.u.P[c][wid * 256 + ks * 32 + g * 8];
#pragma unroll
      for (int dt = 0; dt < 4; ++dt) {
        bf16x8 vf = *(const bf16x8*)(vb + (size_t)dt * 16 * 1024 + ks * 32);
        cacc[dt] = __builtin_amdgcn_mfma_f32_16x16x32_bf16(pf, vf, cacc[dt], 0, 0, 0);
      }
    }
#pragma unroll
    for (int dt = 0; dt < 4; ++dt)
#pragma unroll
      for (int r = 0; r < 4; ++r)
        sm.Cpart[wid][g * 4 + r][dt * 16 + c] = cacc[dt][r];
    __syncthreads();
    for (int i = t; i < 1024; i += 256) {
      int qi = i >> 6, d = i & 63;
      float s = (sm.Cpart[0][qi][d] + sm.Cpart[1][qi][d]) +
                (sm.Cpart[2][qi][d] + sm.Cpart[3][qi][d]);
      CtxG[((size_t)(b * 1024 + q0 + qi)) * 768 + h * 64 + d] = s;
    }
    __syncthreads();
  }

  // ---- importance from head-mean attention, two 8-row halves over P region ----
  float ia[4] = {0.f, 0.f, 0.f, 0.f};
#pragma unroll
  for (int half = 0; half < 2; ++half) {
    if ((g >> 1) == half) {
#pragma unroll
      for (int kt = 0; kt < 16; ++kt)
#pragma unroll
        for (int r = 0; r < 4; ++r)
          sm.u.AW[(g & 1) * 4 + r][wid * 256 + kt * 16 + c] = aw[kt][r];
    }
    __syncthreads();
#pragma unroll
    for (int qi = 0; qi < 8; ++qi) {
#pragma unroll
      for (int cc = 0; cc < 4; ++cc) {
        int k = t * 4 + cc;
        float am = sm.u.AW[qi][k == 0 ? 0 : k - 1];
        float ap = sm.u.AW[qi][k == 1023 ? 1023 : k + 1];
        ia[cc] += fabsf((ap - am) * 0.5f);
      }
    }
    __syncthreads();
  }
#pragma unroll
  for (int cc = 0; cc < 4; ++cc)
    atomicAdd(&Imp[b * 1024 + t * 4 + cc], ia[cc]);
}

// ---------------- conv3 + standardize + softmax(fs/0.1) ----------------
__device__ inline float blk_sum(float v, volatile float* wbuf, int t) {
#pragma unroll
  for (int off = 32; off > 0; off >>= 1) v += __shfl_xor(v, off);
  __syncthreads();
  if ((t & 63) == 0) wbuf[t >> 6] = v;
  __syncthreads();
  return (wbuf[0] + wbuf[1]) + (wbuf[2] + wbuf[3]);
}
__device__ inline float blk_max(float v, volatile float* wbuf, int t) {
#pragma unroll
  for (int off = 32; off > 0; off >>= 1) v = fmaxf(v, __shfl_xor(v, off));
  __syncthreads();
  if ((t & 63) == 0) wbuf[t >> 6] = v;
  __syncthreads();
  return fmaxf(fmaxf(wbuf[0], wbuf[1]), fmaxf(wbuf[2], wbuf[3]));
}

__global__ __launch_bounds__(256)
void scores_kernel(const float* __restrict__ Imp, const float* __restrict__ smw,
                   float* __restrict__ Out)
{
  __shared__ float ip[1026];
  __shared__ float wbuf[4];
  const int b = blockIdx.x;
  const int t = threadIdx.x;

  if (t == 0) { ip[0] = 0.f; ip[1025] = 0.f; }
  float4 iv = *(const float4*)(Imp + (size_t)b * 1024 + t * 4);
  ip[1 + t * 4 + 0] = iv.x;
  ip[1 + t * 4 + 1] = iv.y;
  ip[1 + t * 4 + 2] = iv.z;
  ip[1 + t * 4 + 3] = iv.w;
  __syncthreads();

  const float w0 = smw[0], w1 = smw[1], w2 = smw[2];
  float smv[4];
#pragma unroll
  for (int j = 0; j < 4; ++j) {
    int k = t * 4 + j;
    smv[j] = w0 * ip[k] + w1 * ip[k + 1] + w2 * ip[k + 2];
  }
  float tot = blk_sum((smv[0] + smv[1]) + (smv[2] + smv[3]), wbuf, t);
  float mu  = tot * (1.f / 1024.f);
  float lv = 0.f;
#pragma unroll
  for (int j = 0; j < 4; ++j) { float d = smv[j] - mu; lv += d * d; }
  float var = blk_sum(lv, wbuf, t) * (1.f / 1023.f);
  float inv = 1.f / (sqrtf(var) + 1e-6f);
  float fs[4];
#pragma unroll
  for (int j = 0; j < 4; ++j) fs[j] = (smv[j] - mu) * inv * 10.f;
  float M = blk_max(fmaxf(fmaxf(fs[0], fs[1]), fmaxf(fs[2], fs[3])), wbuf, t);
  float e[4]; float ls = 0.f;
#pragma unroll
  for (int j = 0; j < 4; ++j) { e[j] = __expf(fs[j] - M); ls += e[j]; }
  float S = blk_sum(ls, wbuf, t);
  float r = 1.f / S;
  float4 o = {e[0] * r, e[1] * r, e[2] * r, e[3] * r};
  *(float4*)(Out + (size_t)b * 1024 + t * 4) = o;
}

extern "C" void kernel_launch(void* const* d_in, const int* in_sizes, int n_in,
                              void* d_out, int out_size, void* d_ws, size_t ws_size,
                              hipStream_t stream)
{
  const float* x     = (const float*)d_in[0];
  const float* w_in  = (const float*)d_in[1];
  const float* w_out = (const float*)d_in[2];
  const float* smw   = (const float*)d_in[3];
  float* out = (float*)d_out;

  const size_t SZ = (size_t)BATCH * NSEQ * CDIM;   // 6291456 elements
  unsigned short* qhi = (unsigned short*)d_ws;
  unsigned short* qlo = qhi + SZ;
  unsigned short* khi = qlo + SZ;
  unsigned short* klo = khi + SZ;
  unsigned short* vt  = klo + SZ;
  float* ctx = (float*)(vt + SZ);
  float* imp = ctx + SZ;

  hipMemsetAsync(imp, 0, BATCH * NSEQ * sizeof(float), stream);

  gemm_xwt<0><<<dim3(18, 64), 256, 0, stream>>>(x, w_in, nullptr, qhi, qlo, khi, klo, vt);
  attn_mfma<<<dim3(64, 8), 256, 0, stream>>>(qhi, qlo, khi, klo, vt, ctx, imp);
  gemm_xwt<1><<<dim3(6, 64), 256, 0, stream>>>(ctx, w_out, out,
                                               nullptr, nullptr, nullptr, nullptr, nullptr);
  scores_kernel<<<8, 256, 0, stream>>>(imp, smw, out + SZ);
}

// Round 3
// 524.151 us; speedup vs baseline: 3.5907x; 1.6513x over previous
//
#include <hip/hip_runtime.h>

#define NSEQ  1024
#define NHEAD 12
#define HDIM  64
#define CDIM  768
#define BATCH 8

typedef short bf16x8 __attribute__((ext_vector_type(8)));
typedef float f32x4  __attribute__((ext_vector_type(4)));

__device__ __forceinline__ float bf2f(unsigned short h) {
  unsigned u = ((unsigned)h) << 16;
  float f;
  __builtin_memcpy(&f, &u, 4);
  return f;
}
__device__ __forceinline__ unsigned short f2bf(float f) {
  unsigned u;
  __builtin_memcpy(&u, &f, 4);
  u = (u + 0x7fffu + ((u >> 16) & 1u)) >> 16;
  return (unsigned short)u;
}

// async global->LDS, 16B per lane; data lands at ldsbase + lane*16
#define GLD16(GP, LP) __builtin_amdgcn_global_load_lds( \
    (const __attribute__((address_space(1))) void*)(GP), \
    (__attribute__((address_space(3))) void*)(LP), 16, 0, 0)

// ---------------- fp32 -> bf16 hi/lo conversion pre-pass ----------------
__global__ __launch_bounds__(256)
void convert_kernel(const float* __restrict__ x, const float* __restrict__ w_in,
                    const float* __restrict__ w_out,
                    unsigned short* __restrict__ xh, unsigned short* __restrict__ xl,
                    unsigned short* __restrict__ wih, unsigned short* __restrict__ wil,
                    unsigned short* __restrict__ woh)
{
  const int idx = (blockIdx.x * 256 + threadIdx.x) * 4;
  if (idx < 6291456) {
    float4 v = *(const float4*)(x + idx);
    ushort4 h, l;
    h.x = f2bf(v.x); l.x = f2bf(v.x - bf2f(h.x));
    h.y = f2bf(v.y); l.y = f2bf(v.y - bf2f(h.y));
    h.z = f2bf(v.z); l.z = f2bf(v.z - bf2f(h.z));
    h.w = f2bf(v.w); l.w = f2bf(v.w - bf2f(h.w));
    *(ushort4*)(xh + idx) = h;
    *(ushort4*)(xl + idx) = l;
  } else if (idx < 6291456 + 1769472) {
    const int j = idx - 6291456;
    float4 v = *(const float4*)(w_in + j);
    ushort4 h, l;
    h.x = f2bf(v.x); l.x = f2bf(v.x - bf2f(h.x));
    h.y = f2bf(v.y); l.y = f2bf(v.y - bf2f(h.y));
    h.z = f2bf(v.z); l.z = f2bf(v.z - bf2f(h.z));
    h.w = f2bf(v.w); l.w = f2bf(v.w - bf2f(h.w));
    *(ushort4*)(wih + j) = h;
    *(ushort4*)(wil + j) = l;
  } else {
    const int j = idx - 8060928;
    float4 v = *(const float4*)(w_out + j);
    ushort4 h;
    h.x = f2bf(v.x); h.y = f2bf(v.y); h.z = f2bf(v.z); h.w = f2bf(v.w);
    *(ushort4*)(woh + j) = h;
  }
}

// ---------------- MFMA GEMM: C[M,N] = A[M,768] @ B[N,768]^T ----------------
// Stacked-K hi/lo: K' = 2304 = [Ah.Bh | Al.Bh | Ah.Bl] -> fp32-grade product.
// 128x128 tile, BK=64, 4 waves in 2x2, 4x4 16x16 tiles per wave.
// MODE 0: qkv epilogue (q scaled+split, k split, v transposed bf16).
//         v-section blocks (bn>=12) run single-pass (K=768).
// MODE 1: plain fp32 C write (out-projection), single-pass.
template<int MODE>
__global__ __launch_bounds__(256)
void gemm_mfma(const unsigned short* __restrict__ Ah, const unsigned short* __restrict__ Al,
               const unsigned short* __restrict__ Bh, const unsigned short* __restrict__ Bl,
               float* __restrict__ Cout,
               unsigned short* __restrict__ Qhi, unsigned short* __restrict__ Qlo,
               unsigned short* __restrict__ Khi, unsigned short* __restrict__ Klo,
               unsigned short* __restrict__ Vt)
{
  __shared__ unsigned short Asm[128][64];
  __shared__ unsigned short Bsm[128][64];
  const int t    = threadIdx.x;
  const int lane = t & 63;
  const int wid  = t >> 6;
  const int c    = lane & 15;
  const int g    = lane >> 4;
  const int bn   = blockIdx.x;
  const int bm   = blockIdx.y;
  const int sec    = (MODE == 0) ? (bn / 6) : 0;
  const int nsteps = (MODE == 0 && sec < 2) ? 36 : 12;

  f32x4 acc[4][4];
#pragma unroll
  for (int mi = 0; mi < 4; ++mi)
#pragma unroll
    for (int ni = 0; ni < 4; ++ni) acc[mi][ni] = (f32x4){0.f, 0.f, 0.f, 0.f};

  const size_t Am0 = (size_t)bm * 128;
  const size_t Bn0 = (size_t)bn * 128;
  const int srow = wid * 32 + (lane >> 3);   // + i*8 per issue
  const int scol = (lane & 7) * 8;           // ushort offset within 64-col row
  const int mh = (wid & 1) * 64;
  const int nh = (wid >> 1) * 64;

  for (int ks = 0; ks < nsteps; ++ks) {
    const int ksec = (ks >= 24) ? 2 : ((ks >= 12) ? 1 : 0);
    const int kin  = (ks - ksec * 12) * 64;
    const unsigned short* Asrc = (ksec == 1) ? Al : Ah;
    const unsigned short* Bsrc = (ksec == 2) ? Bl : Bh;
    __syncthreads();
#pragma unroll
    for (int i = 0; i < 4; ++i) {
      GLD16(Asrc + (Am0 + srow + i * 8) * 768 + kin + scol, &Asm[wid * 32 + i * 8][0]);
      GLD16(Bsrc + (Bn0 + srow + i * 8) * 768 + kin + scol, &Bsm[wid * 32 + i * 8][0]);
    }
    __syncthreads();
#pragma unroll
    for (int kk = 0; kk < 2; ++kk) {
      bf16x8 a[4], bb[4];
#pragma unroll
      for (int mi = 0; mi < 4; ++mi)
        a[mi] = *(const bf16x8*)&Asm[mh + mi * 16 + c][kk * 32 + g * 8];
#pragma unroll
      for (int ni = 0; ni < 4; ++ni)
        bb[ni] = *(const bf16x8*)&Bsm[nh + ni * 16 + c][kk * 32 + g * 8];
#pragma unroll
      for (int mi = 0; mi < 4; ++mi)
#pragma unroll
        for (int ni = 0; ni < 4; ++ni)
          acc[mi][ni] = __builtin_amdgcn_mfma_f32_16x16x32_bf16(a[mi], bb[ni], acc[mi][ni], 0, 0, 0);
    }
  }

  // epilogue: C row (g*4+r) = A m-index, col (c) = B n-index
  if (MODE == 1) {
#pragma unroll
    for (int mi = 0; mi < 4; ++mi) {
#pragma unroll
      for (int r = 0; r < 4; ++r) {
        const int m = bm * 128 + mh + mi * 16 + g * 4 + r;
#pragma unroll
        for (int ni = 0; ni < 4; ++ni) {
          const int n = bn * 128 + nh + ni * 16 + c;
          Cout[(size_t)m * 768 + n] = acc[mi][ni][r];
        }
      }
    }
  } else {
#pragma unroll
    for (int mi = 0; mi < 4; ++mi) {
#pragma unroll
      for (int r = 0; r < 4; ++r) {
        const int m   = bm * 128 + mh + mi * 16 + g * 4 + r;
        const int bi  = m >> 10;
        const int qi  = m & 1023;
#pragma unroll
        for (int ni = 0; ni < 4; ++ni) {
          const int n  = bn * 128 + nh + ni * 16 + c;
          const int np = n - sec * 768;
          const int h  = np >> 6;
          const int d  = np & 63;
          const size_t bh = (size_t)(bi * 12 + h);
          float v = acc[mi][ni][r];
          if (sec == 0) {
            v *= 0.125f;                              // pre-scale q by 1/sqrt(64)
            unsigned short hi = f2bf(v);
            Qhi[(bh * 1024 + qi) * 64 + d] = hi;
            Qlo[(bh * 1024 + qi) * 64 + d] = f2bf(v - bf2f(hi));
          } else if (sec == 1) {
            unsigned short hi = f2bf(v);
            Khi[(bh * 1024 + qi) * 64 + d] = hi;
            Klo[(bh * 1024 + qi) * 64 + d] = f2bf(v - bf2f(hi));
          } else {
            Vt[(bh * 64 + d) * 1024 + qi] = f2bf(v);  // transposed for PV B-operand
          }
        }
      }
    }
  }
}

// ---------------- fused MFMA attention + importance ----------------
struct AttnSmem {
  union {
    unsigned short P[16][1040];
    float AW[8][1040];
  } u;
  float Cpart[4][16][64];
  float red[2][16][4];
};

__global__ __launch_bounds__(256, 2)
void attn_mfma(const unsigned short* __restrict__ Qhi, const unsigned short* __restrict__ Qlo,
               const unsigned short* __restrict__ Khi, const unsigned short* __restrict__ Klo,
               const unsigned short* __restrict__ Vt,
               unsigned short* __restrict__ CtxG, float* __restrict__ Imp)
{
  __shared__ AttnSmem sm;
  const int t    = threadIdx.x;
  const int lane = t & 63;
  const int wid  = t >> 6;
  const int g    = lane >> 4;
  const int c    = lane & 15;
  const int qt   = blockIdx.x;
  const int b    = blockIdx.y;
  const int q0   = qt * 16;

  float aw[16][4];
#pragma unroll
  for (int kt = 0; kt < 16; ++kt)
#pragma unroll
    for (int r = 0; r < 4; ++r) aw[kt][r] = 0.f;

  for (int h = 0; h < 12; ++h) {
    const size_t bh = (size_t)b * 12 + h;

    const unsigned short* qp_h = Qhi + (bh * 1024 + q0 + c) * 64 + g * 8;
    const unsigned short* qp_l = Qlo + (bh * 1024 + q0 + c) * 64 + g * 8;
    bf16x8 qh0 = *(const bf16x8*)qp_h;
    bf16x8 qh1 = *(const bf16x8*)(qp_h + 32);
    bf16x8 ql0 = *(const bf16x8*)qp_l;
    bf16x8 ql1 = *(const bf16x8*)(qp_l + 32);

    f32x4 acc[16];
#pragma unroll
    for (int kt = 0; kt < 16; ++kt) acc[kt] = (f32x4){0.f, 0.f, 0.f, 0.f};
    const unsigned short* kp_h = Khi + (bh * 1024 + wid * 256 + c) * 64 + g * 8;
    const unsigned short* kp_l = Klo + (bh * 1024 + wid * 256 + c) * 64 + g * 8;
#pragma unroll
    for (int kt = 0; kt < 16; ++kt) {
      const unsigned short* ph = kp_h + kt * 16 * 64;
      const unsigned short* pl = kp_l + kt * 16 * 64;
      bf16x8 kh0 = *(const bf16x8*)ph;
      bf16x8 kh1 = *(const bf16x8*)(ph + 32);
      bf16x8 kl0 = *(const bf16x8*)pl;
      bf16x8 kl1 = *(const bf16x8*)(pl + 32);
      f32x4 a = acc[kt];
      a = __builtin_amdgcn_mfma_f32_16x16x32_bf16(qh0, kh0, a, 0, 0, 0);
      a = __builtin_amdgcn_mfma_f32_16x16x32_bf16(qh1, kh1, a, 0, 0, 0);
      a = __builtin_amdgcn_mfma_f32_16x16x32_bf16(qh0, kl0, a, 0, 0, 0);
      a = __builtin_amdgcn_mfma_f32_16x16x32_bf16(qh1, kl1, a, 0, 0, 0);
      a = __builtin_amdgcn_mfma_f32_16x16x32_bf16(ql0, kh0, a, 0, 0, 0);
      a = __builtin_amdgcn_mfma_f32_16x16x32_bf16(ql1, kh1, a, 0, 0, 0);
      acc[kt] = a;
    }

    float red4[4];
#pragma unroll
    for (int r = 0; r < 4; ++r) {
      float m = acc[0][r];
#pragma unroll
      for (int kt = 1; kt < 16; ++kt) m = fmaxf(m, acc[kt][r]);
      m = fmaxf(m, __shfl_xor(m, 1));
      m = fmaxf(m, __shfl_xor(m, 2));
      m = fmaxf(m, __shfl_xor(m, 4));
      m = fmaxf(m, __shfl_xor(m, 8));
      red4[r] = m;
    }
    if (c == 0) {
#pragma unroll
      for (int r = 0; r < 4; ++r) sm.red[0][g * 4 + r][wid] = red4[r];
    }
    __syncthreads();
    float M[4];
#pragma unroll
    for (int r = 0; r < 4; ++r) {
      const float* rp = sm.red[0][g * 4 + r];
      M[r] = fmaxf(fmaxf(rp[0], rp[1]), fmaxf(rp[2], rp[3]));
    }
    float sume[4];
#pragma unroll
    for (int r = 0; r < 4; ++r) {
      float s = 0.f;
#pragma unroll
      for (int kt = 0; kt < 16; ++kt) {
        float e = __expf(acc[kt][r] - M[r]);
        acc[kt][r] = e;
        s += e;
      }
      s += __shfl_xor(s, 1);
      s += __shfl_xor(s, 2);
      s += __shfl_xor(s, 4);
      s += __shfl_xor(s, 8);
      sume[r] = s;
    }
    if (c == 0) {
#pragma unroll
      for (int r = 0; r < 4; ++r) sm.red[1][g * 4 + r][wid] = sume[r];
    }
    __syncthreads();
#pragma unroll
    for (int r = 0; r < 4; ++r) {
      const float* rp = sm.red[1][g * 4 + r];
      float inv = 1.f / ((rp[0] + rp[1]) + (rp[2] + rp[3]));
#pragma unroll
      for (int kt = 0; kt < 16; ++kt) {
        float p = acc[kt][r] * inv;
        aw[kt][r] += p * (1.f / 12.f);
        sm.u.P[g * 4 + r][wid * 256 + kt * 16 + c] = f2bf(p);
      }
    }

    f32x4 cacc[4];
#pragma unroll
    for (int dt = 0; dt < 4; ++dt) cacc[dt] = (f32x4){0.f, 0.f, 0.f, 0.f};
    const unsigned short* vb = Vt + (bh * 64 + c) * 1024 + wid * 256 + g * 8;
#pragma unroll
    for (int ks = 0; ks < 8; ++ks) {
      bf16x8 pf = *(const bf16x8*)&sm.u.P[c][wid * 256 + ks * 32 + g * 8];
#pragma unroll
      for (int dt = 0; dt < 4; ++dt) {
        bf16x8 vf = *(const bf16x8*)(vb + (size_t)dt * 16 * 1024 + ks * 32);
        cacc[dt] = __builtin_amdgcn_mfma_f32_16x16x32_bf16(pf, vf, cacc[dt], 0, 0, 0);
      }
    }
#pragma unroll
    for (int dt = 0; dt < 4; ++dt)
#pragma unroll
      for (int r = 0; r < 4; ++r)
        sm.Cpart[wid][g * 4 + r][dt * 16 + c] = cacc[dt][r];
    __syncthreads();
    for (int i = t; i < 1024; i += 256) {
      int qi = i >> 6, d = i & 63;
      float s = (sm.Cpart[0][qi][d] + sm.Cpart[1][qi][d]) +
                (sm.Cpart[2][qi][d] + sm.Cpart[3][qi][d]);
      CtxG[((size_t)(b * 1024 + q0 + qi)) * 768 + h * 64 + d] = f2bf(s);
    }
    __syncthreads();
  }

  float ia[4] = {0.f, 0.f, 0.f, 0.f};
#pragma unroll
  for (int half = 0; half < 2; ++half) {
    if ((g >> 1) == half) {
#pragma unroll
      for (int kt = 0; kt < 16; ++kt)
#pragma unroll
        for (int r = 0; r < 4; ++r)
          sm.u.AW[(g & 1) * 4 + r][wid * 256 + kt * 16 + c] = aw[kt][r];
    }
    __syncthreads();
#pragma unroll
    for (int qi = 0; qi < 8; ++qi) {
#pragma unroll
      for (int cc = 0; cc < 4; ++cc) {
        int k = t * 4 + cc;
        float am = sm.u.AW[qi][k == 0 ? 0 : k - 1];
        float ap = sm.u.AW[qi][k == 1023 ? 1023 : k + 1];
        ia[cc] += fabsf((ap - am) * 0.5f);
      }
    }
    __syncthreads();
  }
#pragma unroll
  for (int cc = 0; cc < 4; ++cc)
    atomicAdd(&Imp[b * 1024 + t * 4 + cc], ia[cc]);
}

// ---------------- conv3 + standardize + softmax(fs/0.1) ----------------
__device__ inline float blk_sum(float v, volatile float* wbuf, int t) {
#pragma unroll
  for (int off = 32; off > 0; off >>= 1) v += __shfl_xor(v, off);
  __syncthreads();
  if ((t & 63) == 0) wbuf[t >> 6] = v;
  __syncthreads();
  return (wbuf[0] + wbuf[1]) + (wbuf[2] + wbuf[3]);
}
__device__ inline float blk_max(float v, volatile float* wbuf, int t) {
#pragma unroll
  for (int off = 32; off > 0; off >>= 1) v = fmaxf(v, __shfl_xor(v, off));
  __syncthreads();
  if ((t & 63) == 0) wbuf[t >> 6] = v;
  __syncthreads();
  return fmaxf(fmaxf(wbuf[0], wbuf[1]), fmaxf(wbuf[2], wbuf[3]));
}

__global__ __launch_bounds__(256)
void scores_kernel(const float* __restrict__ Imp, const float* __restrict__ smw,
                   float* __restrict__ Out)
{
  __shared__ float ip[1026];
  __shared__ float wbuf[4];
  const int b = blockIdx.x;
  const int t = threadIdx.x;

  if (t == 0) { ip[0] = 0.f; ip[1025] = 0.f; }
  float4 iv = *(const float4*)(Imp + (size_t)b * 1024 + t * 4);
  ip[1 + t * 4 + 0] = iv.x;
  ip[1 + t * 4 + 1] = iv.y;
  ip[1 + t * 4 + 2] = iv.z;
  ip[1 + t * 4 + 3] = iv.w;
  __syncthreads();

  const float w0 = smw[0], w1 = smw[1], w2 = smw[2];
  float smv[4];
#pragma unroll
  for (int j = 0; j < 4; ++j) {
    int k = t * 4 + j;
    smv[j] = w0 * ip[k] + w1 * ip[k + 1] + w2 * ip[k + 2];
  }
  float tot = blk_sum((smv[0] + smv[1]) + (smv[2] + smv[3]), wbuf, t);
  float mu  = tot * (1.f / 1024.f);
  float lv = 0.f;
#pragma unroll
  for (int j = 0; j < 4; ++j) { float d = smv[j] - mu; lv += d * d; }
  float var = blk_sum(lv, wbuf, t) * (1.f / 1023.f);
  float inv = 1.f / (sqrtf(var) + 1e-6f);
  float fs[4];
#pragma unroll
  for (int j = 0; j < 4; ++j) fs[j] = (smv[j] - mu) * inv * 10.f;
  float M = blk_max(fmaxf(fmaxf(fs[0], fs[1]), fmaxf(fs[2], fs[3])), wbuf, t);
  float e[4]; float ls = 0.f;
#pragma unroll
  for (int j = 0; j < 4; ++j) { e[j] = __expf(fs[j] - M); ls += e[j]; }
  float S = blk_sum(ls, wbuf, t);
  float r = 1.f / S;
  float4 o = {e[0] * r, e[1] * r, e[2] * r, e[3] * r};
  *(float4*)(Out + (size_t)b * 1024 + t * 4) = o;
}

extern "C" void kernel_launch(void* const* d_in, const int* in_sizes, int n_in,
                              void* d_out, int out_size, void* d_ws, size_t ws_size,
                              hipStream_t stream)
{
  const float* x     = (const float*)d_in[0];
  const float* w_in  = (const float*)d_in[1];
  const float* w_out = (const float*)d_in[2];
  const float* smw   = (const float*)d_in[3];
  float* out = (float*)d_out;

  const size_t SZx  = 6291456;   // 8192*768
  const size_t SZw  = 1769472;   // 2304*768
  const size_t SZwo = 589824;    // 768*768

  unsigned short* xh   = (unsigned short*)d_ws;
  unsigned short* xl   = xh + SZx;
  unsigned short* wih  = xl + SZx;
  unsigned short* wil  = wih + SZw;
  unsigned short* woh  = wil + SZw;
  unsigned short* qhi  = woh + SZwo;
  unsigned short* qlo  = qhi + SZx;
  unsigned short* khi  = qlo + SZx;
  unsigned short* klo  = khi + SZx;
  unsigned short* vt   = klo + SZx;
  unsigned short* ctxb = vt + SZx;
  float* imp = (float*)(ctxb + SZx);

  hipMemsetAsync(imp, 0, BATCH * NSEQ * sizeof(float), stream);

  convert_kernel<<<8448, 256, 0, stream>>>(x, w_in, w_out, xh, xl, wih, wil, woh);
  gemm_mfma<0><<<dim3(18, 64), 256, 0, stream>>>(xh, xl, wih, wil, nullptr,
                                                 qhi, qlo, khi, klo, vt);
  attn_mfma<<<dim3(64, 8), 256, 0, stream>>>(qhi, qlo, khi, klo, vt, ctxb, imp);
  gemm_mfma<1><<<dim3(6, 64), 256, 0, stream>>>(ctxb, nullptr, woh, nullptr, out,
                                                nullptr, nullptr, nullptr, nullptr, nullptr);
  scores_kernel<<<8, 256, 0, stream>>>(imp, smw, out + SZx);
}

// Round 4
// 516.816 us; speedup vs baseline: 3.6416x; 1.0142x over previous
//
#include <hip/hip_runtime.h>

#define NSEQ  1024
#define NHEAD 12
#define HDIM  64
#define CDIM  768
#define BATCH 8

typedef short bf16x8 __attribute__((ext_vector_type(8)));
typedef float f32x4  __attribute__((ext_vector_type(4)));

__device__ __forceinline__ float bf2f(unsigned short h) {
  unsigned u = ((unsigned)h) << 16;
  float f;
  __builtin_memcpy(&f, &u, 4);
  return f;
}
__device__ __forceinline__ unsigned short f2bf(float f) {
  unsigned u;
  __builtin_memcpy(&u, &f, 4);
  u = (u + 0x7fffu + ((u >> 16) & 1u)) >> 16;
  return (unsigned short)u;
}

// async global->LDS, 16B per lane; data lands at ldsbase + lane*16
#define GLD16(GP, LP) __builtin_amdgcn_global_load_lds( \
    (const __attribute__((address_space(1))) void*)(GP), \
    (__attribute__((address_space(3))) void*)(LP), 16, 0, 0)

// ---------------- fp32 -> bf16 hi/lo conversion pre-pass ----------------
__global__ __launch_bounds__(256)
void convert_kernel(const float* __restrict__ x, const float* __restrict__ w_in,
                    const float* __restrict__ w_out,
                    unsigned short* __restrict__ xh, unsigned short* __restrict__ xl,
                    unsigned short* __restrict__ wih, unsigned short* __restrict__ wil,
                    unsigned short* __restrict__ woh)
{
  const int idx = (blockIdx.x * 256 + threadIdx.x) * 4;
  if (idx < 6291456) {
    float4 v = *(const float4*)(x + idx);
    ushort4 h, l;
    h.x = f2bf(v.x); l.x = f2bf(v.x - bf2f(h.x));
    h.y = f2bf(v.y); l.y = f2bf(v.y - bf2f(h.y));
    h.z = f2bf(v.z); l.z = f2bf(v.z - bf2f(h.z));
    h.w = f2bf(v.w); l.w = f2bf(v.w - bf2f(h.w));
    *(ushort4*)(xh + idx) = h;
    *(ushort4*)(xl + idx) = l;
  } else if (idx < 6291456 + 1769472) {
    const int j = idx - 6291456;
    float4 v = *(const float4*)(w_in + j);
    ushort4 h, l;
    h.x = f2bf(v.x); l.x = f2bf(v.x - bf2f(h.x));
    h.y = f2bf(v.y); l.y = f2bf(v.y - bf2f(h.y));
    h.z = f2bf(v.z); l.z = f2bf(v.z - bf2f(h.z));
    h.w = f2bf(v.w); l.w = f2bf(v.w - bf2f(h.w));
    *(ushort4*)(wih + j) = h;
    *(ushort4*)(wil + j) = l;
  } else {
    const int j = idx - 8060928;
    float4 v = *(const float4*)(w_out + j);
    ushort4 h;
    h.x = f2bf(v.x); h.y = f2bf(v.y); h.z = f2bf(v.z); h.w = f2bf(v.w);
    *(ushort4*)(woh + j) = h;
  }
}

// ---------------- MFMA GEMM: C[M,N] = A[M,768] @ B[N,768]^T ----------------
// Stacked-K hi/lo: K' = 2304 = [Ah.Bh | Al.Bh | Ah.Bl] -> fp32-grade product.
// 128x128 tile, BK=64, 4 waves in 2x2, 4x4 16x16 tiles per wave.
template<int MODE>
__global__ __launch_bounds__(256)
void gemm_mfma(const unsigned short* __restrict__ Ah, const unsigned short* __restrict__ Al,
               const unsigned short* __restrict__ Bh, const unsigned short* __restrict__ Bl,
               float* __restrict__ Cout,
               unsigned short* __restrict__ Qhi, unsigned short* __restrict__ Qlo,
               unsigned short* __restrict__ Khi, unsigned short* __restrict__ Klo,
               unsigned short* __restrict__ Vt)
{
  __shared__ unsigned short Asm[128][64];
  __shared__ unsigned short Bsm[128][64];
  const int t    = threadIdx.x;
  const int lane = t & 63;
  const int wid  = t >> 6;
  const int c    = lane & 15;
  const int g    = lane >> 4;
  const int bn   = blockIdx.x;
  const int bm   = blockIdx.y;
  const int sec    = (MODE == 0) ? (bn / 6) : 0;
  const int nsteps = (MODE == 0 && sec < 2) ? 36 : 12;

  f32x4 acc[4][4];
#pragma unroll
  for (int mi = 0; mi < 4; ++mi)
#pragma unroll
    for (int ni = 0; ni < 4; ++ni) acc[mi][ni] = (f32x4){0.f, 0.f, 0.f, 0.f};

  const size_t Am0 = (size_t)bm * 128;
  const size_t Bn0 = (size_t)bn * 128;
  const int srow = wid * 32 + (lane >> 3);
  const int scol = (lane & 7) * 8;
  const int mh = (wid & 1) * 64;
  const int nh = (wid >> 1) * 64;

  for (int ks = 0; ks < nsteps; ++ks) {
    const int ksec = (ks >= 24) ? 2 : ((ks >= 12) ? 1 : 0);
    const int kin  = (ks - ksec * 12) * 64;
    const unsigned short* Asrc = (ksec == 1) ? Al : Ah;
    const unsigned short* Bsrc = (ksec == 2) ? Bl : Bh;
    __syncthreads();
#pragma unroll
    for (int i = 0; i < 4; ++i) {
      GLD16(Asrc + (Am0 + srow + i * 8) * 768 + kin + scol, &Asm[wid * 32 + i * 8][0]);
      GLD16(Bsrc + (Bn0 + srow + i * 8) * 768 + kin + scol, &Bsm[wid * 32 + i * 8][0]);
    }
    __syncthreads();
#pragma unroll
    for (int kk = 0; kk < 2; ++kk) {
      bf16x8 a[4], bb[4];
#pragma unroll
      for (int mi = 0; mi < 4; ++mi)
        a[mi] = *(const bf16x8*)&Asm[mh + mi * 16 + c][kk * 32 + g * 8];
#pragma unroll
      for (int ni = 0; ni < 4; ++ni)
        bb[ni] = *(const bf16x8*)&Bsm[nh + ni * 16 + c][kk * 32 + g * 8];
#pragma unroll
      for (int mi = 0; mi < 4; ++mi)
#pragma unroll
        for (int ni = 0; ni < 4; ++ni)
          acc[mi][ni] = __builtin_amdgcn_mfma_f32_16x16x32_bf16(a[mi], bb[ni], acc[mi][ni], 0, 0, 0);
    }
  }

  if (MODE == 1) {
#pragma unroll
    for (int mi = 0; mi < 4; ++mi) {
#pragma unroll
      for (int r = 0; r < 4; ++r) {
        const int m = bm * 128 + mh + mi * 16 + g * 4 + r;
#pragma unroll
        for (int ni = 0; ni < 4; ++ni) {
          const int n = bn * 128 + nh + ni * 16 + c;
          Cout[(size_t)m * 768 + n] = acc[mi][ni][r];
        }
      }
    }
  } else {
#pragma unroll
    for (int mi = 0; mi < 4; ++mi) {
#pragma unroll
      for (int r = 0; r < 4; ++r) {
        const int m   = bm * 128 + mh + mi * 16 + g * 4 + r;
        const int bi  = m >> 10;
        const int qi  = m & 1023;
#pragma unroll
        for (int ni = 0; ni < 4; ++ni) {
          const int n  = bn * 128 + nh + ni * 16 + c;
          const int np = n - sec * 768;
          const int h  = np >> 6;
          const int d  = np & 63;
          const size_t bh = (size_t)(bi * 12 + h);
          float v = acc[mi][ni][r];
          if (sec == 0) {
            v *= 0.125f;
            unsigned short hi = f2bf(v);
            Qhi[(bh * 1024 + qi) * 64 + d] = hi;
            Qlo[(bh * 1024 + qi) * 64 + d] = f2bf(v - bf2f(hi));
          } else if (sec == 1) {
            unsigned short hi = f2bf(v);
            Khi[(bh * 1024 + qi) * 64 + d] = hi;
            Klo[(bh * 1024 + qi) * 64 + d] = f2bf(v - bf2f(hi));
          } else {
            Vt[(bh * 64 + d) * 1024 + qi] = f2bf(v);
          }
        }
      }
    }
  }
}

// ---------------- fused MFMA attention + importance ----------------
// 1D grid of 512: b = id & 7 (XCD-affinity: per-batch K/V stays in one XCD's L2),
// qt = id >> 3. P/AW row stride 1032 ushorts (516 dwords % 32 = 4 -> 2-way only).
struct AttnSmem {
  union {
    unsigned short P[16][1032];
    float AW[8][1032];
  } u;
  float Cpart[4][16][64];
  float red[2][16][4];
};

__global__ __launch_bounds__(256, 2)
void attn_mfma(const unsigned short* __restrict__ Qhi, const unsigned short* __restrict__ Qlo,
               const unsigned short* __restrict__ Khi, const unsigned short* __restrict__ Klo,
               const unsigned short* __restrict__ Vt,
               unsigned short* __restrict__ CtxG, float* __restrict__ Imp)
{
  __shared__ AttnSmem sm;
  const int t    = threadIdx.x;
  const int lane = t & 63;
  const int wid  = t >> 6;
  const int g    = lane >> 4;
  const int c    = lane & 15;
  const int b    = blockIdx.x & 7;    // XCD-affinity swizzle
  const int qt   = blockIdx.x >> 3;
  const int q0   = qt * 16;

  float aw[16][4];
#pragma unroll
  for (int kt = 0; kt < 16; ++kt)
#pragma unroll
    for (int r = 0; r < 4; ++r) aw[kt][r] = 0.f;

  for (int h = 0; h < 12; ++h) {
    const size_t bh = (size_t)b * 12 + h;

    const unsigned short* qp_h = Qhi + (bh * 1024 + q0 + c) * 64 + g * 8;
    const unsigned short* qp_l = Qlo + (bh * 1024 + q0 + c) * 64 + g * 8;
    bf16x8 qh0 = *(const bf16x8*)qp_h;
    bf16x8 qh1 = *(const bf16x8*)(qp_h + 32);
    bf16x8 ql0 = *(const bf16x8*)qp_l;
    bf16x8 ql1 = *(const bf16x8*)(qp_l + 32);

    f32x4 acc[16];
#pragma unroll
    for (int kt = 0; kt < 16; ++kt) acc[kt] = (f32x4){0.f, 0.f, 0.f, 0.f};
    const unsigned short* kp_h = Khi + (bh * 1024 + wid * 256 + c) * 64 + g * 8;
    const unsigned short* kp_l = Klo + (bh * 1024 + wid * 256 + c) * 64 + g * 8;
#pragma unroll
    for (int kt = 0; kt < 16; ++kt) {
      const unsigned short* ph = kp_h + kt * 16 * 64;
      const unsigned short* pl = kp_l + kt * 16 * 64;
      bf16x8 kh0 = *(const bf16x8*)ph;
      bf16x8 kh1 = *(const bf16x8*)(ph + 32);
      bf16x8 kl0 = *(const bf16x8*)pl;
      bf16x8 kl1 = *(const bf16x8*)(pl + 32);
      f32x4 a = acc[kt];
      a = __builtin_amdgcn_mfma_f32_16x16x32_bf16(qh0, kh0, a, 0, 0, 0);
      a = __builtin_amdgcn_mfma_f32_16x16x32_bf16(qh1, kh1, a, 0, 0, 0);
      a = __builtin_amdgcn_mfma_f32_16x16x32_bf16(qh0, kl0, a, 0, 0, 0);
      a = __builtin_amdgcn_mfma_f32_16x16x32_bf16(qh1, kl1, a, 0, 0, 0);
      a = __builtin_amdgcn_mfma_f32_16x16x32_bf16(ql0, kh0, a, 0, 0, 0);
      a = __builtin_amdgcn_mfma_f32_16x16x32_bf16(ql1, kh1, a, 0, 0, 0);
      acc[kt] = a;
    }

    float red4[4];
#pragma unroll
    for (int r = 0; r < 4; ++r) {
      float m = acc[0][r];
#pragma unroll
      for (int kt = 1; kt < 16; ++kt) m = fmaxf(m, acc[kt][r]);
      m = fmaxf(m, __shfl_xor(m, 1));
      m = fmaxf(m, __shfl_xor(m, 2));
      m = fmaxf(m, __shfl_xor(m, 4));
      m = fmaxf(m, __shfl_xor(m, 8));
      red4[r] = m;
    }
    if (c == 0) {
#pragma unroll
      for (int r = 0; r < 4; ++r) sm.red[0][g * 4 + r][wid] = red4[r];
    }
    __syncthreads();
    float M[4];
#pragma unroll
    for (int r = 0; r < 4; ++r) {
      const float* rp = sm.red[0][g * 4 + r];
      M[r] = fmaxf(fmaxf(rp[0], rp[1]), fmaxf(rp[2], rp[3]));
    }
    float sume[4];
#pragma unroll
    for (int r = 0; r < 4; ++r) {
      float s = 0.f;
#pragma unroll
      for (int kt = 0; kt < 16; ++kt) {
        float e = __expf(acc[kt][r] - M[r]);
        acc[kt][r] = e;
        s += e;
      }
      s += __shfl_xor(s, 1);
      s += __shfl_xor(s, 2);
      s += __shfl_xor(s, 4);
      s += __shfl_xor(s, 8);
      sume[r] = s;
    }
    if (c == 0) {
#pragma unroll
      for (int r = 0; r < 4; ++r) sm.red[1][g * 4 + r][wid] = sume[r];
    }
    __syncthreads();
#pragma unroll
    for (int r = 0; r < 4; ++r) {
      const float* rp = sm.red[1][g * 4 + r];
      float inv = 1.f / ((rp[0] + rp[1]) + (rp[2] + rp[3]));
#pragma unroll
      for (int kt = 0; kt < 16; ++kt) {
        float p = acc[kt][r] * inv;
        aw[kt][r] += p * (1.f / 12.f);
        sm.u.P[g * 4 + r][wid * 256 + kt * 16 + c] = f2bf(p);
      }
    }

    f32x4 cacc[4];
#pragma unroll
    for (int dt = 0; dt < 4; ++dt) cacc[dt] = (f32x4){0.f, 0.f, 0.f, 0.f};
    const unsigned short* vb = Vt + (bh * 64 + c) * 1024 + wid * 256 + g * 8;
#pragma unroll
    for (int ks = 0; ks < 8; ++ks) {
      bf16x8 pf = *(const bf16x8*)&sm.u.P[c][wid * 256 + ks * 32 + g * 8];
#pragma unroll
      for (int dt = 0; dt < 4; ++dt) {
        bf16x8 vf = *(const bf16x8*)(vb + (size_t)dt * 16 * 1024 + ks * 32);
        cacc[dt] = __builtin_amdgcn_mfma_f32_16x16x32_bf16(pf, vf, cacc[dt], 0, 0, 0);
      }
    }
#pragma unroll
    for (int dt = 0; dt < 4; ++dt)
#pragma unroll
      for (int r = 0; r < 4; ++r)
        sm.Cpart[wid][g * 4 + r][dt * 16 + c] = cacc[dt][r];
    __syncthreads();
    for (int i = t; i < 1024; i += 256) {
      int qi = i >> 6, d = i & 63;
      float s = (sm.Cpart[0][qi][d] + sm.Cpart[1][qi][d]) +
                (sm.Cpart[2][qi][d] + sm.Cpart[3][qi][d]);
      CtxG[((size_t)(b * 1024 + q0 + qi)) * 768 + h * 64 + d] = f2bf(s);
    }
    __syncthreads();
  }

  float ia[4] = {0.f, 0.f, 0.f, 0.f};
#pragma unroll
  for (int half = 0; half < 2; ++half) {
    if ((g >> 1) == half) {
#pragma unroll
      for (int kt = 0; kt < 16; ++kt)
#pragma unroll
        for (int r = 0; r < 4; ++r)
          sm.u.AW[(g & 1) * 4 + r][wid * 256 + kt * 16 + c] = aw[kt][r];
    }
    __syncthreads();
#pragma unroll
    for (int qi = 0; qi < 8; ++qi) {
#pragma unroll
      for (int cc = 0; cc < 4; ++cc) {
        int k = t * 4 + cc;
        float am = sm.u.AW[qi][k == 0 ? 0 : k - 1];
        float ap = sm.u.AW[qi][k == 1023 ? 1023 : k + 1];
        ia[cc] += fabsf((ap - am) * 0.5f);
      }
    }
    __syncthreads();
  }
#pragma unroll
  for (int cc = 0; cc < 4; ++cc)
    atomicAdd(&Imp[b * 1024 + t * 4 + cc], ia[cc]);
}

// ---------------- conv3 + standardize + softmax(fs/0.1) ----------------
__device__ inline float blk_sum(float v, volatile float* wbuf, int t) {
#pragma unroll
  for (int off = 32; off > 0; off >>= 1) v += __shfl_xor(v, off);
  __syncthreads();
  if ((t & 63) == 0) wbuf[t >> 6] = v;
  __syncthreads();
  return (wbuf[0] + wbuf[1]) + (wbuf[2] + wbuf[3]);
}
__device__ inline float blk_max(float v, volatile float* wbuf, int t) {
#pragma unroll
  for (int off = 32; off > 0; off >>= 1) v = fmaxf(v, __shfl_xor(v, off));
  __syncthreads();
  if ((t & 63) == 0) wbuf[t >> 6] = v;
  __syncthreads();
  return fmaxf(fmaxf(wbuf[0], wbuf[1]), fmaxf(wbuf[2], wbuf[3]));
}

__global__ __launch_bounds__(256)
void scores_kernel(const float* __restrict__ Imp, const float* __restrict__ smw,
                   float* __restrict__ Out)
{
  __shared__ float ip[1026];
  __shared__ float wbuf[4];
  const int b = blockIdx.x;
  const int t = threadIdx.x;

  if (t == 0) { ip[0] = 0.f; ip[1025] = 0.f; }
  float4 iv = *(const float4*)(Imp + (size_t)b * 1024 + t * 4);
  ip[1 + t * 4 + 0] = iv.x;
  ip[1 + t * 4 + 1] = iv.y;
  ip[1 + t * 4 + 2] = iv.z;
  ip[1 + t * 4 + 3] = iv.w;
  __syncthreads();

  const float w0 = smw[0], w1 = smw[1], w2 = smw[2];
  float smv[4];
#pragma unroll
  for (int j = 0; j < 4; ++j) {
    int k = t * 4 + j;
    smv[j] = w0 * ip[k] + w1 * ip[k + 1] + w2 * ip[k + 2];
  }
  float tot = blk_sum((smv[0] + smv[1]) + (smv[2] + smv[3]), wbuf, t);
  float mu  = tot * (1.f / 1024.f);
  float lv = 0.f;
#pragma unroll
  for (int j = 0; j < 4; ++j) { float d = smv[j] - mu; lv += d * d; }
  float var = blk_sum(lv, wbuf, t) * (1.f / 1023.f);
  float inv = 1.f / (sqrtf(var) + 1e-6f);
  float fs[4];
#pragma unroll
  for (int j = 0; j < 4; ++j) fs[j] = (smv[j] - mu) * inv * 10.f;
  float M = blk_max(fmaxf(fmaxf(fs[0], fs[1]), fmaxf(fs[2], fs[3])), wbuf, t);
  float e[4]; float ls = 0.f;
#pragma unroll
  for (int j = 0; j < 4; ++j) { e[j] = __expf(fs[j] - M); ls += e[j]; }
  float S = blk_sum(ls, wbuf, t);
  float r = 1.f / S;
  float4 o = {e[0] * r, e[1] * r, e[2] * r, e[3] * r};
  *(float4*)(Out + (size_t)b * 1024 + t * 4) = o;
}

extern "C" void kernel_launch(void* const* d_in, const int* in_sizes, int n_in,
                              void* d_out, int out_size, void* d_ws, size_t ws_size,
                              hipStream_t stream)
{
  const float* x     = (const float*)d_in[0];
  const float* w_in  = (const float*)d_in[1];
  const float* w_out = (const float*)d_in[2];
  const float* smw   = (const float*)d_in[3];
  float* out = (float*)d_out;

  const size_t SZx  = 6291456;   // 8192*768
  const size_t SZw  = 1769472;   // 2304*768
  const size_t SZwo = 589824;    // 768*768

  unsigned short* xh   = (unsigned short*)d_ws;
  unsigned short* xl   = xh + SZx;
  unsigned short* wih  = xl + SZx;
  unsigned short* wil  = wih + SZw;
  unsigned short* woh  = wil + SZw;
  unsigned short* qhi  = woh + SZwo;
  unsigned short* qlo  = qhi + SZx;
  unsigned short* khi  = qlo + SZx;
  unsigned short* klo  = khi + SZx;
  unsigned short* vt   = klo + SZx;
  unsigned short* ctxb = vt + SZx;
  float* imp = (float*)(ctxb + SZx);

  hipMemsetAsync(imp, 0, BATCH * NSEQ * sizeof(float), stream);

  convert_kernel<<<8448, 256, 0, stream>>>(x, w_in, w_out, xh, xl, wih, wil, woh);
  gemm_mfma<0><<<dim3(18, 64), 256, 0, stream>>>(xh, xl, wih, wil, nullptr,
                                                 qhi, qlo, khi, klo, vt);
  attn_mfma<<<512, 256, 0, stream>>>(qhi, qlo, khi, klo, vt, ctxb, imp);
  gemm_mfma<1><<<dim3(6, 64), 256, 0, stream>>>(ctxb, nullptr, woh, nullptr, out,
                                                nullptr, nullptr, nullptr, nullptr, nullptr);
  scores_kernel<<<8, 256, 0, stream>>>(imp, smw, out + SZx);
}